// Round 8
// baseline (229.899 us; speedup 1.0000x reference)
//
#include <hip/hip_runtime.h>
#include <hip/hip_fp16.h>

#define DIM 768
#define NH 12
#define HD 64
#define B_ 8
#define N_ 1024
#define BH (B_*NH)
#define EPS 1e-5f
// fold 1/sqrt(64) * log2(e) into q at pack time -> scores arrive in exp2 domain
#define QSCALE 0.18033688011112042f
#define CVT_BLOCKS 576   // DIM*DIM/4/256 exactly

typedef short s16x8 __attribute__((ext_vector_type(8)));
typedef _Float16 f16x8 __attribute__((ext_vector_type(8)));
typedef float f32x4 __attribute__((ext_vector_type(4)));

__device__ __forceinline__ unsigned pk2h(float a, float b) {
    __half2 h = __floats2half2_rn(a, b);
    union { __half2 h; unsigned u; } cv; cv.h = h;
    return cv.u;
}

__device__ __forceinline__ float h2f(unsigned us) {
    __half_raw hr; hr.x = (unsigned short)(us & 0xffffu);
    return __half2float(__half(hr));
}

__device__ __forceinline__ f16x8 asf(s16x8 x) {
    union { s16x8 s; f16x8 f; } u; u.s = x; return u.f;
}

__device__ __forceinline__ float fexp2(float x) {
#if __has_builtin(__builtin_amdgcn_exp2f)
    return __builtin_amdgcn_exp2f(x);
#else
    return exp2f(x);
#endif
}

__device__ __forceinline__ void async_cp16(const void* g, void* l) {
    __builtin_amdgcn_global_load_lds(
        (const __attribute__((address_space(1))) unsigned*)g,
        (__attribute__((address_space(3))) unsigned*)l, 16, 0, 0);
}

// pack 4 floats into hi fp16 pair-words + UNSCALED-lo fp16 pair-words.
// Residuals |lo| <= ulp(hi)/2; tiny residuals may denormal-flush (error <= 6.1e-5
// absolute) -- harmless since lo feeds a same-accumulator chained MFMA.
__device__ __forceinline__ void split4u(float a0, float a1, float a2, float a3,
                                        unsigned& uh0, unsigned& uh1,
                                        unsigned& ul0, unsigned& ul1) {
    uh0 = pk2h(a0, a1); uh1 = pk2h(a2, a3);
    ul0 = pk2h(a0 - h2f(uh0), a1 - h2f(uh0 >> 16));
    ul1 = pk2h(a2 - h2f(uh1), a3 - h2f(uh1 >> 16));
}

// ---------------- Kernel 1: LayerNorm q,k + split-fp16 pack (+ fused W cvt tail) -----
// LANE-LINEAR fragment layout: within each 512-elem (16-row x 32-kdim) MFMA fragment,
// lane l's 16B chunk lives at byte l*16 (chunk (row r, kchunk q) at elem (q*16+r)*8).
// Phase order: load q,k -> reduce -> issue v loads -> split/write q,k (v latency
// hides under this VALU) -> v split -> LDS transpose. Shrinks peak VGPR liveness.
__global__ __launch_bounds__(256)
void ln_pack_kernel(const float* __restrict__ QKV,
                    const float* __restrict__ qw, const float* __restrict__ qb,
                    const float* __restrict__ kw, const float* __restrict__ kb,
                    unsigned short* __restrict__ Qh, unsigned short* __restrict__ Ql,
                    unsigned short* __restrict__ Kh, unsigned short* __restrict__ Kl,
                    unsigned short* __restrict__ Vh, unsigned short* __restrict__ Vl,
                    const float* __restrict__ pw, unsigned short* __restrict__ Wb) {
    int bid = blockIdx.x;
    int tid = threadIdx.x;
    if (bid >= BH * 16) {        // fused cvt tail: proj_w fp32 -> fp16 (exact coverage)
        int i = (bid - BH * 16) * 256 + tid;
        float4 f = *(const float4*)(pw + (size_t)i * 4);
        uint2 u; u.x = pk2h(f.x, f.y); u.y = pk2h(f.z, f.w);
        *(uint2*)(Wb + (size_t)i * 4) = u;
        return;
    }
    int bh = bid >> 4, nt = bid & 15;
    int b = bh / NH, h = bh % NH;
    int w = tid >> 6, ln = tid & 63;
    int rl = w * 16 + (ln >> 2);     // local row 0..63
    int part = ln & 3;               // dims part*16 .. part*16+15
    int n = nt * 64 + rl;

    __shared__ __attribute__((aligned(16))) unsigned short vldsh[64][72];
    __shared__ __attribute__((aligned(16))) unsigned short vldsl[64][72];

    size_t base = ((size_t)(b * N_ + n)) * (3 * DIM) + h * HD + part * 16;
    float4 q[4], k[4];
    #pragma unroll
    for (int i = 0; i < 4; i++) {
        q[i] = *(const float4*)(QKV + base + i * 4);
        k[i] = *(const float4*)(QKV + base + DIM + i * 4);
    }

    float s1 = 0.f, s2 = 0.f, t1 = 0.f, t2 = 0.f;
    #pragma unroll
    for (int i = 0; i < 4; i++) {
        s1 += (q[i].x + q[i].y) + (q[i].z + q[i].w);
        s2 += (q[i].x * q[i].x + q[i].y * q[i].y) + (q[i].z * q[i].z + q[i].w * q[i].w);
        t1 += (k[i].x + k[i].y) + (k[i].z + k[i].w);
        t2 += (k[i].x * k[i].x + k[i].y * k[i].y) + (k[i].z * k[i].z + k[i].w * k[i].w);
    }
    #pragma unroll
    for (int m = 1; m < 4; m <<= 1) {
        s1 += __shfl_xor(s1, m, 64);
        s2 += __shfl_xor(s2, m, 64);
        t1 += __shfl_xor(t1, m, 64);
        t2 += __shfl_xor(t2, m, 64);
    }

    // issue v loads now; consumed after the q/k split phases (latency hidden there)
    float4 v[4];
    #pragma unroll
    for (int i = 0; i < 4; i++)
        v[i] = *(const float4*)(QKV + base + 2 * DIM + i * 4);

    int ch = part >> 1;
    int q0 = (part & 1) * 2;         // k-chunk index (within fragment) of c0; c1 = q0+1
    int r16 = n & 15;                // row within 16-row fragment
    size_t frag = (((size_t)bh * 64 + (n >> 4)) * 2 + ch) * 512;
    size_t off0 = frag + (size_t)(q0 * 16 + r16) * 8;
    size_t off1 = frag + (size_t)((q0 + 1) * 16 + r16) * 8;

    {   // q: hi + unscaled-lo
        float mu = s1 * (1.0f / 64.0f);
        float var = s2 * (1.0f / 64.0f) - mu * mu;
        float rstd = rsqrtf(var + EPS);
        s16x8 h0, h1, l0, l1;
        #pragma unroll
        for (int i = 0; i < 4; i++) {
            const float4 wv = *(const float4*)(qw + part * 16 + i * 4);
            const float4 bv = *(const float4*)(qb + part * 16 + i * 4);
            float a0 = ((q[i].x - mu) * rstd * wv.x + bv.x) * QSCALE;
            float a1 = ((q[i].y - mu) * rstd * wv.y + bv.y) * QSCALE;
            float a2 = ((q[i].z - mu) * rstd * wv.z + bv.z) * QSCALE;
            float a3 = ((q[i].w - mu) * rstd * wv.w + bv.w) * QSCALE;
            unsigned uh0, uh1, ul0, ul1;
            split4u(a0, a1, a2, a3, uh0, uh1, ul0, ul1);
            if (i < 2) {
                ((unsigned*)&h0)[i * 2] = uh0; ((unsigned*)&h0)[i * 2 + 1] = uh1;
                ((unsigned*)&l0)[i * 2] = ul0; ((unsigned*)&l0)[i * 2 + 1] = ul1;
            } else {
                ((unsigned*)&h1)[(i - 2) * 2] = uh0; ((unsigned*)&h1)[(i - 2) * 2 + 1] = uh1;
                ((unsigned*)&l1)[(i - 2) * 2] = ul0; ((unsigned*)&l1)[(i - 2) * 2 + 1] = ul1;
            }
        }
        *(s16x8*)(Qh + off0) = h0;  *(s16x8*)(Qh + off1) = h1;
        *(s16x8*)(Ql + off0) = l0;  *(s16x8*)(Ql + off1) = l1;
    }
    {   // k: hi + unscaled-lo
        float mu = t1 * (1.0f / 64.0f);
        float var = t2 * (1.0f / 64.0f) - mu * mu;
        float rstd = rsqrtf(var + EPS);
        s16x8 h0, h1, l0, l1;
        #pragma unroll
        for (int i = 0; i < 4; i++) {
            const float4 wv = *(const float4*)(kw + part * 16 + i * 4);
            const float4 bv = *(const float4*)(kb + part * 16 + i * 4);
            float a0 = (k[i].x - mu) * rstd * wv.x + bv.x;
            float a1 = (k[i].y - mu) * rstd * wv.y + bv.y;
            float a2 = (k[i].z - mu) * rstd * wv.z + bv.z;
            float a3 = (k[i].w - mu) * rstd * wv.w + bv.w;
            unsigned uh0, uh1, ul0, ul1;
            split4u(a0, a1, a2, a3, uh0, uh1, ul0, ul1);
            if (i < 2) {
                ((unsigned*)&h0)[i * 2] = uh0; ((unsigned*)&h0)[i * 2 + 1] = uh1;
                ((unsigned*)&l0)[i * 2] = ul0; ((unsigned*)&l0)[i * 2 + 1] = ul1;
            } else {
                ((unsigned*)&h1)[(i - 2) * 2] = uh0; ((unsigned*)&h1)[(i - 2) * 2 + 1] = uh1;
                ((unsigned*)&l1)[(i - 2) * 2] = ul0; ((unsigned*)&l1)[(i - 2) * 2 + 1] = ul1;
            }
        }
        *(s16x8*)(Kh + off0) = h0;  *(s16x8*)(Kh + off1) = h1;
        *(s16x8*)(Kl + off0) = l0;  *(s16x8*)(Kl + off1) = l1;
    }
    {   // v -> LDS (hi + unscaled-lo fp16)
        s16x8 h0, h1, l0, l1;
        #pragma unroll
        for (int i = 0; i < 4; i++) {
            unsigned uh0, uh1, ul0, ul1;
            split4u(v[i].x, v[i].y, v[i].z, v[i].w, uh0, uh1, ul0, ul1);
            if (i < 2) {
                ((unsigned*)&h0)[i * 2] = uh0; ((unsigned*)&h0)[i * 2 + 1] = uh1;
                ((unsigned*)&l0)[i * 2] = ul0; ((unsigned*)&l0)[i * 2 + 1] = ul1;
            } else {
                ((unsigned*)&h1)[(i - 2) * 2] = uh0; ((unsigned*)&h1)[(i - 2) * 2 + 1] = uh1;
                ((unsigned*)&l1)[(i - 2) * 2] = ul0; ((unsigned*)&l1)[(i - 2) * 2 + 1] = ul1;
            }
        }
        *(s16x8*)&vldsh[rl][part * 16] = h0;  *(s16x8*)&vldsh[rl][part * 16 + 8] = h1;
        *(s16x8*)&vldsl[rl][part * 16] = l0;  *(s16x8*)&vldsl[rl][part * 16 + 8] = l1;
    }
    __syncthreads();
    // Vh/Vl: permuted transpose into lane-linear fragments; each thread writes the
    // chunk (kchunk q=pq, row r=d&15) of fragment t=d>>4 of its 32-key group.
    #pragma unroll
    for (int cc = 0; cc < 2; cc++) {
        int c = tid * 2 + cc;
        int pq = c & 3, d = (c >> 2) & 63, nb = c >> 8;
        s16x8 oh, ol;
        #pragma unroll
        for (int jj = 0; jj < 4; jj++) {
            oh[jj]     = (short)vldsh[nb * 32 + pq * 4 + jj][d];
            oh[4 + jj] = (short)vldsh[nb * 32 + 16 + pq * 4 + jj][d];
            ol[jj]     = (short)vldsl[nb * 32 + pq * 4 + jj][d];
            ol[4 + jj] = (short)vldsl[nb * 32 + 16 + pq * 4 + jj][d];
        }
        size_t off = ((size_t)bh * 32 + nt * 2 + nb) * 2048
                   + (size_t)(d >> 4) * 512 + (size_t)(pq * 16 + (d & 15)) * 8;
        *(s16x8*)(Vh + off) = oh;
        *(s16x8*)(Vl + off) = ol;
    }
}

// ---------------- Kernel 3: flash attention, compensated fp16 via chained MFMA -------
// Scores: s = (qh+ql)·(kh+kl) minus lo*lo, all four MFMA products chained into ONE
// fp32 accumulator (lo terms first). PV: o = (Vh+Vl)·Ph chained likewise. P raw fp16
// with consistent ones-row-MFMA normalization.
// 64-key double-buffered staging for Kh/Kl/Vh (48 KB LDS -> 3 blocks/CU); V-lo from
// global into registers. Lane-linear fragments: ds_read_b128 conflict-free.
// Launched as TWO dispatches (mt_base 0 and 4) so ln_pack/proj surface in rocprof
// top-5 with counters -- the non-attn ~150us has been invisible for 6 rounds.
__global__ __launch_bounds__(256, 3)
void attn_kernel(const unsigned short* __restrict__ Qhp, const unsigned short* __restrict__ Qlp,
                 const unsigned short* __restrict__ Khp, const unsigned short* __restrict__ Klp,
                 const unsigned short* __restrict__ Vhp, const unsigned short* __restrict__ Vlp,
                 unsigned short* __restrict__ Xb, int mt_base) {
    int bid = blockIdx.x;
    int bh = bid % BH;           // same-head blocks 96 apart -> same XCD
    int mt = mt_base + bid / BH; // 0..3 or 4..7
    int b = bh / NH, h = bh % NH;
    int tid = threadIdx.x;
    int w = tid >> 6, ln = tid & 63;
    int l16 = ln & 15, quad = ln >> 4;
    int lo8 = ln * 8;            // lane-linear fragment offset (elems)

    // 2 buffers x [Kh 4096 | Kl 4096 | Vh 4096] shorts = 48 KB total
    __shared__ __attribute__((aligned(16))) unsigned short Sh[2][12288];
    unsigned short (*Ol)[16][72] = (unsigned short (*)[16][72])&Sh[0][0];  // epilogue alias

    const unsigned short* Qhb = Qhp + (size_t)bh * 65536;
    const unsigned short* Qlb = Qlp + (size_t)bh * 65536;
    const unsigned short* Khb = Khp + (size_t)bh * 65536;
    const unsigned short* Klb = Klp + (size_t)bh * 65536;
    const unsigned short* Vhb = Vhp + (size_t)bh * 65536;
    const unsigned short* Vlb = Vlp + (size_t)bh * 65536;

    int m0 = mt * 128 + w * 32;

    s16x8 qfh[2][2], qfl[2][2];
    #pragma unroll
    for (int si = 0; si < 2; si++)
        #pragma unroll
        for (int ch = 0; ch < 2; ch++) {
            size_t qo = (size_t)((mt * 8 + w * 2 + si) * 2 + ch) * 512 + lo8;
            qfh[si][ch] = *(const s16x8*)(Qhb + qo);
            qfl[si][ch] = *(const s16x8*)(Qlb + qo);
        }

    const s16x8 ones = {0x3C00, 0x3C00, 0x3C00, 0x3C00, 0x3C00, 0x3C00, 0x3C00, 0x3C00};

    f32x4 o[2][4], o4[2];
    #pragma unroll
    for (int si = 0; si < 2; si++) {
        #pragma unroll
        for (int t = 0; t < 4; t++) o[si][t] = (f32x4){0.f,0.f,0.f,0.f};
        o4[si] = (f32x4){0.f,0.f,0.f,0.f};
    }

    // stage 24KB for 64 keys at n0 into Sh[s]: waves 0,1,2 stage Kh/Kl/Vh (8KB each);
    // wave 3 issues nothing (DMA BW, not issue rate, is the limit)
#define STAGE(s, n0)                                                              \
    {                                                                             \
        if (w < 3) {                                                              \
            const unsigned short* gsrc;                                           \
            if (w == 0)      gsrc = Khb + (size_t)((n0) >> 4) * 1024 + ln * 8;    \
            else if (w == 1) gsrc = Klb + (size_t)((n0) >> 4) * 1024 + ln * 8;    \
            else             gsrc = Vhb + (size_t)((n0) >> 5) * 2048 + ln * 8;    \
            _Pragma("unroll") for (int j = 0; j < 8; j++)                         \
                async_cp16(gsrc + j * 512, &Sh[s][w * 4096 + j * 512]);           \
        }                                                                         \
    }

    STAGE(0, 0);
    for (int n0 = 0; n0 < N_; n0 += 64) {
        int cur = (n0 >> 6) & 1;
        __syncthreads();                     // buf[cur] DMA complete; prior reads drained
        if (n0 + 64 < N_) STAGE(cur ^ 1, n0 + 64);

        const unsigned short* KsH = &Sh[cur][0];
        const unsigned short* KsL = &Sh[cur][4096];
        const unsigned short* VsH = &Sh[cur][8192];
        #pragma unroll
        for (int h2 = 0; h2 < 2; h2++) {     // two 32-key halves
            s16x8 kfh[2][2], kfl[2][2];
            #pragma unroll
            for (int kh = 0; kh < 2; kh++)
                #pragma unroll
                for (int ch = 0; ch < 2; ch++) {
                    int to = ((h2 * 2 + kh) * 2 + ch) * 512 + lo8;
                    kfh[kh][ch] = *(const s16x8*)(KsH + to);
                    kfl[kh][ch] = *(const s16x8*)(KsL + to);
                }
            s16x8 vfh[4], vfl[4];
            #pragma unroll
            for (int t = 0; t < 4; t++) {
                int vo = t * 512 + lo8;
                vfh[t] = *(const s16x8*)(VsH + h2 * 2048 + vo);
                vfl[t] = *(const s16x8*)(Vlb + ((size_t)(n0 >> 5) + h2) * 2048 + vo);
            }

            #pragma unroll
            for (int si = 0; si < 2; si++) {
                // chained compensated QK^T: lo terms first, hi last (fp32 accum)
                f32x4 st0 = (f32x4){0.f,0.f,0.f,0.f};
                st0 = __builtin_amdgcn_mfma_f32_16x16x32_f16(asf(kfl[0][0]), asf(qfh[si][0]), st0, 0, 0, 0);
                st0 = __builtin_amdgcn_mfma_f32_16x16x32_f16(asf(kfl[0][1]), asf(qfh[si][1]), st0, 0, 0, 0);
                st0 = __builtin_amdgcn_mfma_f32_16x16x32_f16(asf(kfh[0][0]), asf(qfl[si][0]), st0, 0, 0, 0);
                st0 = __builtin_amdgcn_mfma_f32_16x16x32_f16(asf(kfh[0][1]), asf(qfl[si][1]), st0, 0, 0, 0);
                st0 = __builtin_amdgcn_mfma_f32_16x16x32_f16(asf(kfh[0][0]), asf(qfh[si][0]), st0, 0, 0, 0);
                st0 = __builtin_amdgcn_mfma_f32_16x16x32_f16(asf(kfh[0][1]), asf(qfh[si][1]), st0, 0, 0, 0);
                f32x4 st1 = (f32x4){0.f,0.f,0.f,0.f};
                st1 = __builtin_amdgcn_mfma_f32_16x16x32_f16(asf(kfl[1][0]), asf(qfh[si][0]), st1, 0, 0, 0);
                st1 = __builtin_amdgcn_mfma_f32_16x16x32_f16(asf(kfl[1][1]), asf(qfh[si][1]), st1, 0, 0, 0);
                st1 = __builtin_amdgcn_mfma_f32_16x16x32_f16(asf(kfh[1][0]), asf(qfl[si][0]), st1, 0, 0, 0);
                st1 = __builtin_amdgcn_mfma_f32_16x16x32_f16(asf(kfh[1][1]), asf(qfl[si][1]), st1, 0, 0, 0);
                st1 = __builtin_amdgcn_mfma_f32_16x16x32_f16(asf(kfh[1][0]), asf(qfh[si][0]), st1, 0, 0, 0);
                st1 = __builtin_amdgcn_mfma_f32_16x16x32_f16(asf(kfh[1][1]), asf(qfh[si][1]), st1, 0, 0, 0);

                float p0 = fexp2(st0[0]), p1 = fexp2(st0[1]);
                float p2 = fexp2(st0[2]), p3 = fexp2(st0[3]);
                float p4 = fexp2(st1[0]), p5 = fexp2(st1[1]);
                float p6 = fexp2(st1[2]), p7 = fexp2(st1[3]);
                union { uint4 u; s16x8 s; } ph;
                ph.u.x = pk2h(p0, p1); ph.u.y = pk2h(p2, p3);
                ph.u.z = pk2h(p4, p5); ph.u.w = pk2h(p6, p7);

                #pragma unroll
                for (int t = 0; t < 4; t++) {
                    o[si][t] = __builtin_amdgcn_mfma_f32_16x16x32_f16(asf(vfl[t]), asf(ph.s), o[si][t], 0, 0, 0);
                    o[si][t] = __builtin_amdgcn_mfma_f32_16x16x32_f16(asf(vfh[t]), asf(ph.s), o[si][t], 0, 0, 0);
                }
                o4[si] = __builtin_amdgcn_mfma_f32_16x16x32_f16(asf(ones), asf(ph.s), o4[si], 0, 0, 0);
            }
        }
    }
#undef STAGE

    __syncthreads();  // staging reads done before Ol (aliased) is written
    #pragma unroll
    for (int si = 0; si < 2; si++) {
        float inv = 1.0f / o4[si][0];        // l for qrow l16 (all 4 elems equal)
        #pragma unroll
        for (int t = 0; t < 4; t++) {
            uint2 u;
            u.x = pk2h(o[si][t][0] * inv, o[si][t][1] * inv);
            u.y = pk2h(o[si][t][2] * inv, o[si][t][3] * inv);
            *(uint2*)&Ol[w][l16][t * 16 + quad * 4] = u;
        }
        s16x8 r0 = *(const s16x8*)&Ol[w][l16][quad * 16];
        s16x8 r1 = *(const s16x8*)&Ol[w][l16][quad * 16 + 8];
        size_t row = (size_t)b * N_ + m0 + si * 16 + l16;
        *(s16x8*)(Xb + row * DIM + h * HD + quad * 16) = r0;
        *(s16x8*)(Xb + row * DIM + h * HD + quad * 16 + 8) = r1;
    }
}

// ---------------- Kernel 4: projection GEMM, double-buffered LDS (attn-style) --------
__global__ __launch_bounds__(256, 3)
void proj_kernel(const unsigned short* __restrict__ Xb,
                 const unsigned short* __restrict__ Wb,
                 const float* __restrict__ pb,
                 float* __restrict__ out) {
    int bid = blockIdx.x;
    int bm = bid % 64, bn = bid / 64;   // same-bm blocks 64 apart -> same XCD (A L2 reuse)
    int tid = threadIdx.x, w = tid >> 6, ln = tid & 63;
    int l16 = ln & 15, quad = ln >> 4;
    int wm = w & 1, wn = w >> 1;

    __shared__ __attribute__((aligned(16))) unsigned short As[2][128 * 64];
    __shared__ __attribute__((aligned(16))) unsigned short Bs[2][64 * 64];

    int lr = ln >> 3;            // row-within-DMA-instr 0..7
    int gc = (ln & 7) ^ lr;      // swizzled global chunk this lane fetches

    const unsigned short* Ag = Xb + (size_t)(bm * 128 + w * 32 + lr) * DIM + gc * 8;
    const unsigned short* Bg = Wb + (size_t)(bn * 64 + w * 16 + lr) * DIM + gc * 8;

    f32x4 c[4][2];
    #pragma unroll
    for (int t = 0; t < 4; t++)
        #pragma unroll
        for (int u = 0; u < 2; u++) c[t][u] = (f32x4){0.f, 0.f, 0.f, 0.f};

    int sw = l16 & 7;            // row-swizzle term for fragment reads

#define PSTAGE(s, kk)                                                             \
    {                                                                             \
        _Pragma("unroll") for (int j = 0; j < 4; j++)                             \
            async_cp16(Ag + (size_t)j * 8 * DIM + (kk), &As[s][(w * 32 + j * 8) * 64]); \
        _Pragma("unroll") for (int j = 0; j < 2; j++)                             \
            async_cp16(Bg + (size_t)j * 8 * DIM + (kk), &Bs[s][(w * 16 + j * 8) * 64]); \
    }

    PSTAGE(0, 0);
    for (int it = 0; it < DIM / 64; it++) {
        int cur = it & 1;
        __syncthreads();                     // buf[cur] DMA complete; prior reads drained
        if (it + 1 < DIM / 64) PSTAGE(cur ^ 1, (it + 1) * 64);

        #pragma unroll
        for (int kh = 0; kh < 2; kh++) {
            s16x8 af[4], bf[2];
            #pragma unroll
            for (int t = 0; t < 4; t++) {
                int m = wm * 64 + t * 16 + l16;
                af[t] = *(const s16x8*)(&As[cur][m * 64 + (((kh * 4 + quad) ^ sw) * 8)]);
            }
            #pragma unroll
            for (int u = 0; u < 2; u++) {
                int n = wn * 32 + u * 16 + l16;
                bf[u] = *(const s16x8*)(&Bs[cur][n * 64 + (((kh * 4 + quad) ^ sw) * 8)]);
            }
            #pragma unroll
            for (int t = 0; t < 4; t++)
                #pragma unroll
                for (int u = 0; u < 2; u++)
                    c[t][u] = __builtin_amdgcn_mfma_f32_16x16x32_f16(asf(af[t]), asf(bf[u]), c[t][u], 0, 0, 0);
        }
    }
#undef PSTAGE

    int m0 = bm * 128 + wm * 64;
    int n0 = bn * 64 + wn * 32;
    #pragma unroll
    for (int u = 0; u < 2; u++) {
        float bias = pb[n0 + u * 16 + l16];
        #pragma unroll
        for (int t = 0; t < 4; t++)
            #pragma unroll
            for (int r = 0; r < 4; r++) {
                int row = m0 + t * 16 + quad * 4 + r;
                out[(size_t)row * DIM + n0 + u * 16 + l16] = c[t][u][r] + bias;
            }
    }
}

extern "C" void kernel_launch(void* const* d_in, const int* in_sizes, int n_in,
                              void* d_out, int out_size, void* d_ws, size_t ws_size,
                              hipStream_t stream) {
    const float* QKV = (const float*)d_in[0];
    const float* qw  = (const float*)d_in[1];
    const float* qb  = (const float*)d_in[2];
    const float* kw  = (const float*)d_in[3];
    const float* kb  = (const float*)d_in[4];
    const float* pw  = (const float*)d_in[5];
    const float* pb  = (const float*)d_in[6];
    float* out = (float*)d_out;

    size_t S = (size_t)BH * 65536;
    unsigned short* Qh = (unsigned short*)d_ws;
    unsigned short* Ql = Qh + S;
    unsigned short* Kh = Ql + S;
    unsigned short* Kl = Kh + S;
    unsigned short* Vh = Kl + S;
    unsigned short* Vl = Vh + S;
    unsigned short* Xb = Vl + S;                                // 8192*768
    unsigned short* Wb = Xb + (size_t)B_ * N_ * DIM;            // 768*768

    ln_pack_kernel<<<BH * 16 + CVT_BLOCKS, 256, 0, stream>>>(QKV, qw, qb, kw, kb,
                                                             Qh, Ql, Kh, Kl, Vh, Vl, pw, Wb);
    attn_kernel<<<BH * 4, 256, 0, stream>>>(Qh, Ql, Kh, Kl, Vh, Vl, Xb, 0);
    attn_kernel<<<BH * 4, 256, 0, stream>>>(Qh, Ql, Kh, Kl, Vh, Vl, Xb, 4);
    proj_kernel<<<64 * 12, 256, 0, stream>>>(Xb, Wb, pb, out);
}

// Round 9
// 209.796 us; speedup vs baseline: 1.0958x; 1.0958x over previous
//
#include <hip/hip_runtime.h>
#include <hip/hip_fp16.h>

#define DIM 768
#define NH 12
#define HD 64
#define B_ 8
#define N_ 1024
#define BH (B_*NH)
#define EPS 1e-5f
// fold 1/sqrt(64) * log2(e) into q at pack time -> scores arrive in exp2 domain
#define QSCALE 0.18033688011112042f
#define CVT_BLOCKS 576   // DIM*DIM/4/256 exactly

typedef short s16x8 __attribute__((ext_vector_type(8)));
typedef _Float16 f16x8 __attribute__((ext_vector_type(8)));
typedef float f32x4 __attribute__((ext_vector_type(4)));

__device__ __forceinline__ unsigned pk2h(float a, float b) {
    __half2 h = __floats2half2_rn(a, b);
    union { __half2 h; unsigned u; } cv; cv.h = h;
    return cv.u;
}

__device__ __forceinline__ float h2f(unsigned us) {
    __half_raw hr; hr.x = (unsigned short)(us & 0xffffu);
    return __half2float(__half(hr));
}

__device__ __forceinline__ f16x8 asf(s16x8 x) {
    union { s16x8 s; f16x8 f; } u; u.s = x; return u.f;
}

__device__ __forceinline__ float fexp2(float x) {
#if __has_builtin(__builtin_amdgcn_exp2f)
    return __builtin_amdgcn_exp2f(x);
#else
    return exp2f(x);
#endif
}

__device__ __forceinline__ void async_cp16(const void* g, void* l) {
    __builtin_amdgcn_global_load_lds(
        (const __attribute__((address_space(1))) unsigned*)g,
        (__attribute__((address_space(3))) unsigned*)l, 16, 0, 0);
}

// pack 4 floats into hi fp16 pair-words + UNSCALED-lo fp16 pair-words.
// Residuals |lo| <= ulp(hi)/2; tiny residuals may denormal-flush (error <= 6.1e-5
// absolute) -- harmless since lo feeds a same-accumulator chained MFMA.
__device__ __forceinline__ void split4u(float a0, float a1, float a2, float a3,
                                        unsigned& uh0, unsigned& uh1,
                                        unsigned& ul0, unsigned& ul1) {
    uh0 = pk2h(a0, a1); uh1 = pk2h(a2, a3);
    ul0 = pk2h(a0 - h2f(uh0), a1 - h2f(uh0 >> 16));
    ul1 = pk2h(a2 - h2f(uh1), a3 - h2f(uh1 >> 16));
}

// ---------------- Kernel 1: LayerNorm q,k + split-fp16 pack (+ fused W cvt tail) -----
// LANE-LINEAR fragment layout: within each 512-elem (16-row x 32-kdim) MFMA fragment,
// lane l's 16B chunk lives at byte l*16 (chunk (row r, kchunk q) at elem (q*16+r)*8).
// All 12 global loads issued upfront (max memory-level parallelism -- the round-8
// "reorder" that delayed v-loads behind the shfl chain cost ~10us; reverted).
__global__ __launch_bounds__(256)
void ln_pack_kernel(const float* __restrict__ QKV,
                    const float* __restrict__ qw, const float* __restrict__ qb,
                    const float* __restrict__ kw, const float* __restrict__ kb,
                    unsigned short* __restrict__ Qh, unsigned short* __restrict__ Ql,
                    unsigned short* __restrict__ Kh, unsigned short* __restrict__ Kl,
                    unsigned short* __restrict__ Vh, unsigned short* __restrict__ Vl,
                    const float* __restrict__ pw, unsigned short* __restrict__ Wb) {
    int bid = blockIdx.x;
    int tid = threadIdx.x;
    if (bid >= BH * 16) {        // fused cvt tail: proj_w fp32 -> fp16 (exact coverage)
        int i = (bid - BH * 16) * 256 + tid;
        float4 f = *(const float4*)(pw + (size_t)i * 4);
        uint2 u; u.x = pk2h(f.x, f.y); u.y = pk2h(f.z, f.w);
        *(uint2*)(Wb + (size_t)i * 4) = u;
        return;
    }
    int bh = bid >> 4, nt = bid & 15;
    int b = bh / NH, h = bh % NH;
    int w = tid >> 6, ln = tid & 63;
    int rl = w * 16 + (ln >> 2);     // local row 0..63
    int part = ln & 3;               // dims part*16 .. part*16+15
    int n = nt * 64 + rl;

    __shared__ __attribute__((aligned(16))) unsigned short vldsh[64][72];
    __shared__ __attribute__((aligned(16))) unsigned short vldsl[64][72];

    size_t base = ((size_t)(b * N_ + n)) * (3 * DIM) + h * HD + part * 16;
    float4 q[4], k[4], v[4];
    #pragma unroll
    for (int i = 0; i < 4; i++) {
        q[i] = *(const float4*)(QKV + base + i * 4);
        k[i] = *(const float4*)(QKV + base + DIM + i * 4);
        v[i] = *(const float4*)(QKV + base + 2 * DIM + i * 4);
    }

    float s1 = 0.f, s2 = 0.f, t1 = 0.f, t2 = 0.f;
    #pragma unroll
    for (int i = 0; i < 4; i++) {
        s1 += (q[i].x + q[i].y) + (q[i].z + q[i].w);
        s2 += (q[i].x * q[i].x + q[i].y * q[i].y) + (q[i].z * q[i].z + q[i].w * q[i].w);
        t1 += (k[i].x + k[i].y) + (k[i].z + k[i].w);
        t2 += (k[i].x * k[i].x + k[i].y * k[i].y) + (k[i].z * k[i].z + k[i].w * k[i].w);
    }
    #pragma unroll
    for (int m = 1; m < 4; m <<= 1) {
        s1 += __shfl_xor(s1, m, 64);
        s2 += __shfl_xor(s2, m, 64);
        t1 += __shfl_xor(t1, m, 64);
        t2 += __shfl_xor(t2, m, 64);
    }

    int ch = part >> 1;
    int q0 = (part & 1) * 2;         // k-chunk index (within fragment) of c0; c1 = q0+1
    int r16 = n & 15;                // row within 16-row fragment
    size_t frag = (((size_t)bh * 64 + (n >> 4)) * 2 + ch) * 512;
    size_t off0 = frag + (size_t)(q0 * 16 + r16) * 8;
    size_t off1 = frag + (size_t)((q0 + 1) * 16 + r16) * 8;

    {   // q: hi + unscaled-lo
        float mu = s1 * (1.0f / 64.0f);
        float var = s2 * (1.0f / 64.0f) - mu * mu;
        float rstd = rsqrtf(var + EPS);
        s16x8 h0, h1, l0, l1;
        #pragma unroll
        for (int i = 0; i < 4; i++) {
            const float4 wv = *(const float4*)(qw + part * 16 + i * 4);
            const float4 bv = *(const float4*)(qb + part * 16 + i * 4);
            float a0 = ((q[i].x - mu) * rstd * wv.x + bv.x) * QSCALE;
            float a1 = ((q[i].y - mu) * rstd * wv.y + bv.y) * QSCALE;
            float a2 = ((q[i].z - mu) * rstd * wv.z + bv.z) * QSCALE;
            float a3 = ((q[i].w - mu) * rstd * wv.w + bv.w) * QSCALE;
            unsigned uh0, uh1, ul0, ul1;
            split4u(a0, a1, a2, a3, uh0, uh1, ul0, ul1);
            if (i < 2) {
                ((unsigned*)&h0)[i * 2] = uh0; ((unsigned*)&h0)[i * 2 + 1] = uh1;
                ((unsigned*)&l0)[i * 2] = ul0; ((unsigned*)&l0)[i * 2 + 1] = ul1;
            } else {
                ((unsigned*)&h1)[(i - 2) * 2] = uh0; ((unsigned*)&h1)[(i - 2) * 2 + 1] = uh1;
                ((unsigned*)&l1)[(i - 2) * 2] = ul0; ((unsigned*)&l1)[(i - 2) * 2 + 1] = ul1;
            }
        }
        *(s16x8*)(Qh + off0) = h0;  *(s16x8*)(Qh + off1) = h1;
        *(s16x8*)(Ql + off0) = l0;  *(s16x8*)(Ql + off1) = l1;
    }
    {   // k: hi + unscaled-lo
        float mu = t1 * (1.0f / 64.0f);
        float var = t2 * (1.0f / 64.0f) - mu * mu;
        float rstd = rsqrtf(var + EPS);
        s16x8 h0, h1, l0, l1;
        #pragma unroll
        for (int i = 0; i < 4; i++) {
            const float4 wv = *(const float4*)(kw + part * 16 + i * 4);
            const float4 bv = *(const float4*)(kb + part * 16 + i * 4);
            float a0 = (k[i].x - mu) * rstd * wv.x + bv.x;
            float a1 = (k[i].y - mu) * rstd * wv.y + bv.y;
            float a2 = (k[i].z - mu) * rstd * wv.z + bv.z;
            float a3 = (k[i].w - mu) * rstd * wv.w + bv.w;
            unsigned uh0, uh1, ul0, ul1;
            split4u(a0, a1, a2, a3, uh0, uh1, ul0, ul1);
            if (i < 2) {
                ((unsigned*)&h0)[i * 2] = uh0; ((unsigned*)&h0)[i * 2 + 1] = uh1;
                ((unsigned*)&l0)[i * 2] = ul0; ((unsigned*)&l0)[i * 2 + 1] = ul1;
            } else {
                ((unsigned*)&h1)[(i - 2) * 2] = uh0; ((unsigned*)&h1)[(i - 2) * 2 + 1] = uh1;
                ((unsigned*)&l1)[(i - 2) * 2] = ul0; ((unsigned*)&l1)[(i - 2) * 2 + 1] = ul1;
            }
        }
        *(s16x8*)(Kh + off0) = h0;  *(s16x8*)(Kh + off1) = h1;
        *(s16x8*)(Kl + off0) = l0;  *(s16x8*)(Kl + off1) = l1;
    }
    {   // v -> LDS (hi + unscaled-lo fp16)
        s16x8 h0, h1, l0, l1;
        #pragma unroll
        for (int i = 0; i < 4; i++) {
            unsigned uh0, uh1, ul0, ul1;
            split4u(v[i].x, v[i].y, v[i].z, v[i].w, uh0, uh1, ul0, ul1);
            if (i < 2) {
                ((unsigned*)&h0)[i * 2] = uh0; ((unsigned*)&h0)[i * 2 + 1] = uh1;
                ((unsigned*)&l0)[i * 2] = ul0; ((unsigned*)&l0)[i * 2 + 1] = ul1;
            } else {
                ((unsigned*)&h1)[(i - 2) * 2] = uh0; ((unsigned*)&h1)[(i - 2) * 2 + 1] = uh1;
                ((unsigned*)&l1)[(i - 2) * 2] = ul0; ((unsigned*)&l1)[(i - 2) * 2 + 1] = ul1;
            }
        }
        *(s16x8*)&vldsh[rl][part * 16] = h0;  *(s16x8*)&vldsh[rl][part * 16 + 8] = h1;
        *(s16x8*)&vldsl[rl][part * 16] = l0;  *(s16x8*)&vldsl[rl][part * 16 + 8] = l1;
    }
    __syncthreads();
    // Vh/Vl: permuted transpose into lane-linear fragments; each thread writes the
    // chunk (kchunk q=pq, row r=d&15) of fragment t=d>>4 of its 32-key group.
    #pragma unroll
    for (int cc = 0; cc < 2; cc++) {
        int c = tid * 2 + cc;
        int pq = c & 3, d = (c >> 2) & 63, nb = c >> 8;
        s16x8 oh, ol;
        #pragma unroll
        for (int jj = 0; jj < 4; jj++) {
            oh[jj]     = (short)vldsh[nb * 32 + pq * 4 + jj][d];
            oh[4 + jj] = (short)vldsh[nb * 32 + 16 + pq * 4 + jj][d];
            ol[jj]     = (short)vldsl[nb * 32 + pq * 4 + jj][d];
            ol[4 + jj] = (short)vldsl[nb * 32 + 16 + pq * 4 + jj][d];
        }
        size_t off = ((size_t)bh * 32 + nt * 2 + nb) * 2048
                   + (size_t)(d >> 4) * 512 + (size_t)(pq * 16 + (d & 15)) * 8;
        *(s16x8*)(Vh + off) = oh;
        *(s16x8*)(Vl + off) = ol;
    }
}

// ---------------- Kernel 3: flash attention, compensated fp16 via chained MFMA -------
// Round-6 body exactly (59.5us known-good): single dispatch, no setprio.
// Scores: s = (qh+ql)·(kh+kl) minus lo*lo, chained into ONE fp32 accumulator (lo
// first). PV: o = (Vh+Vl)·Ph chained. P raw fp16 with ones-row-MFMA normalization.
// 64-key double-buffered Kh/Kl/Vh staging (48 KB -> 3 blocks/CU); V-lo from global.
// Lane-linear fragments: ds_read_b128 conflict-free.
__global__ __launch_bounds__(256, 3)
void attn_kernel(const unsigned short* __restrict__ Qhp, const unsigned short* __restrict__ Qlp,
                 const unsigned short* __restrict__ Khp, const unsigned short* __restrict__ Klp,
                 const unsigned short* __restrict__ Vhp, const unsigned short* __restrict__ Vlp,
                 unsigned short* __restrict__ Xb) {
    int bid = blockIdx.x;
    int bh = bid % BH;           // same-head blocks 96 apart -> same XCD
    int mt = bid / BH;           // 0..7
    int b = bh / NH, h = bh % NH;
    int tid = threadIdx.x;
    int w = tid >> 6, ln = tid & 63;
    int l16 = ln & 15, quad = ln >> 4;
    int lo8 = ln * 8;            // lane-linear fragment offset (elems)

    // 2 buffers x [Kh 4096 | Kl 4096 | Vh 4096] shorts = 48 KB total
    __shared__ __attribute__((aligned(16))) unsigned short Sh[2][12288];
    unsigned short (*Ol)[16][72] = (unsigned short (*)[16][72])&Sh[0][0];  // epilogue alias

    const unsigned short* Qhb = Qhp + (size_t)bh * 65536;
    const unsigned short* Qlb = Qlp + (size_t)bh * 65536;
    const unsigned short* Khb = Khp + (size_t)bh * 65536;
    const unsigned short* Klb = Klp + (size_t)bh * 65536;
    const unsigned short* Vhb = Vhp + (size_t)bh * 65536;
    const unsigned short* Vlb = Vlp + (size_t)bh * 65536;

    int m0 = mt * 128 + w * 32;

    s16x8 qfh[2][2], qfl[2][2];
    #pragma unroll
    for (int si = 0; si < 2; si++)
        #pragma unroll
        for (int ch = 0; ch < 2; ch++) {
            size_t qo = (size_t)((mt * 8 + w * 2 + si) * 2 + ch) * 512 + lo8;
            qfh[si][ch] = *(const s16x8*)(Qhb + qo);
            qfl[si][ch] = *(const s16x8*)(Qlb + qo);
        }

    const s16x8 ones = {0x3C00, 0x3C00, 0x3C00, 0x3C00, 0x3C00, 0x3C00, 0x3C00, 0x3C00};

    f32x4 o[2][4], o4[2];
    #pragma unroll
    for (int si = 0; si < 2; si++) {
        #pragma unroll
        for (int t = 0; t < 4; t++) o[si][t] = (f32x4){0.f,0.f,0.f,0.f};
        o4[si] = (f32x4){0.f,0.f,0.f,0.f};
    }

    // stage 24KB for 64 keys at n0 into Sh[s]: waves 0,1,2 stage Kh/Kl/Vh (8KB each);
    // wave 3 issues nothing (DMA BW, not issue rate, is the limit)
#define STAGE(s, n0)                                                              \
    {                                                                             \
        if (w < 3) {                                                              \
            const unsigned short* gsrc;                                           \
            if (w == 0)      gsrc = Khb + (size_t)((n0) >> 4) * 1024 + ln * 8;    \
            else if (w == 1) gsrc = Klb + (size_t)((n0) >> 4) * 1024 + ln * 8;    \
            else             gsrc = Vhb + (size_t)((n0) >> 5) * 2048 + ln * 8;    \
            _Pragma("unroll") for (int j = 0; j < 8; j++)                         \
                async_cp16(gsrc + j * 512, &Sh[s][w * 4096 + j * 512]);           \
        }                                                                         \
    }

    STAGE(0, 0);
    for (int n0 = 0; n0 < N_; n0 += 64) {
        int cur = (n0 >> 6) & 1;
        __syncthreads();                     // buf[cur] DMA complete; prior reads drained
        if (n0 + 64 < N_) STAGE(cur ^ 1, n0 + 64);

        const unsigned short* KsH = &Sh[cur][0];
        const unsigned short* KsL = &Sh[cur][4096];
        const unsigned short* VsH = &Sh[cur][8192];
        #pragma unroll
        for (int h2 = 0; h2 < 2; h2++) {     // two 32-key halves
            s16x8 kfh[2][2], kfl[2][2];
            #pragma unroll
            for (int kh = 0; kh < 2; kh++)
                #pragma unroll
                for (int ch = 0; ch < 2; ch++) {
                    int to = ((h2 * 2 + kh) * 2 + ch) * 512 + lo8;
                    kfh[kh][ch] = *(const s16x8*)(KsH + to);
                    kfl[kh][ch] = *(const s16x8*)(KsL + to);
                }
            s16x8 vfh[4], vfl[4];
            #pragma unroll
            for (int t = 0; t < 4; t++) {
                int vo = t * 512 + lo8;
                vfh[t] = *(const s16x8*)(VsH + h2 * 2048 + vo);
                vfl[t] = *(const s16x8*)(Vlb + ((size_t)(n0 >> 5) + h2) * 2048 + vo);
            }

            #pragma unroll
            for (int si = 0; si < 2; si++) {
                // chained compensated QK^T: lo terms first, hi last (fp32 accum)
                f32x4 st0 = (f32x4){0.f,0.f,0.f,0.f};
                st0 = __builtin_amdgcn_mfma_f32_16x16x32_f16(asf(kfl[0][0]), asf(qfh[si][0]), st0, 0, 0, 0);
                st0 = __builtin_amdgcn_mfma_f32_16x16x32_f16(asf(kfl[0][1]), asf(qfh[si][1]), st0, 0, 0, 0);
                st0 = __builtin_amdgcn_mfma_f32_16x16x32_f16(asf(kfh[0][0]), asf(qfl[si][0]), st0, 0, 0, 0);
                st0 = __builtin_amdgcn_mfma_f32_16x16x32_f16(asf(kfh[0][1]), asf(qfl[si][1]), st0, 0, 0, 0);
                st0 = __builtin_amdgcn_mfma_f32_16x16x32_f16(asf(kfh[0][0]), asf(qfh[si][0]), st0, 0, 0, 0);
                st0 = __builtin_amdgcn_mfma_f32_16x16x32_f16(asf(kfh[0][1]), asf(qfh[si][1]), st0, 0, 0, 0);
                f32x4 st1 = (f32x4){0.f,0.f,0.f,0.f};
                st1 = __builtin_amdgcn_mfma_f32_16x16x32_f16(asf(kfl[1][0]), asf(qfh[si][0]), st1, 0, 0, 0);
                st1 = __builtin_amdgcn_mfma_f32_16x16x32_f16(asf(kfl[1][1]), asf(qfh[si][1]), st1, 0, 0, 0);
                st1 = __builtin_amdgcn_mfma_f32_16x16x32_f16(asf(kfh[1][0]), asf(qfl[si][0]), st1, 0, 0, 0);
                st1 = __builtin_amdgcn_mfma_f32_16x16x32_f16(asf(kfh[1][1]), asf(qfl[si][1]), st1, 0, 0, 0);
                st1 = __builtin_amdgcn_mfma_f32_16x16x32_f16(asf(kfh[1][0]), asf(qfh[si][0]), st1, 0, 0, 0);
                st1 = __builtin_amdgcn_mfma_f32_16x16x32_f16(asf(kfh[1][1]), asf(qfh[si][1]), st1, 0, 0, 0);

                float p0 = fexp2(st0[0]), p1 = fexp2(st0[1]);
                float p2 = fexp2(st0[2]), p3 = fexp2(st0[3]);
                float p4 = fexp2(st1[0]), p5 = fexp2(st1[1]);
                float p6 = fexp2(st1[2]), p7 = fexp2(st1[3]);
                union { uint4 u; s16x8 s; } ph;
                ph.u.x = pk2h(p0, p1); ph.u.y = pk2h(p2, p3);
                ph.u.z = pk2h(p4, p5); ph.u.w = pk2h(p6, p7);

                #pragma unroll
                for (int t = 0; t < 4; t++) {
                    o[si][t] = __builtin_amdgcn_mfma_f32_16x16x32_f16(asf(vfl[t]), asf(ph.s), o[si][t], 0, 0, 0);
                    o[si][t] = __builtin_amdgcn_mfma_f32_16x16x32_f16(asf(vfh[t]), asf(ph.s), o[si][t], 0, 0, 0);
                }
                o4[si] = __builtin_amdgcn_mfma_f32_16x16x32_f16(asf(ones), asf(ph.s), o4[si], 0, 0, 0);
            }
        }
    }
#undef STAGE

    __syncthreads();  // staging reads done before Ol (aliased) is written
    #pragma unroll
    for (int si = 0; si < 2; si++) {
        float inv = 1.0f / o4[si][0];        // l for qrow l16 (all 4 elems equal)
        #pragma unroll
        for (int t = 0; t < 4; t++) {
            uint2 u;
            u.x = pk2h(o[si][t][0] * inv, o[si][t][1] * inv);
            u.y = pk2h(o[si][t][2] * inv, o[si][t][3] * inv);
            *(uint2*)&Ol[w][l16][t * 16 + quad * 4] = u;
        }
        s16x8 r0 = *(const s16x8*)&Ol[w][l16][quad * 16];
        s16x8 r1 = *(const s16x8*)&Ol[w][l16][quad * 16 + 8];
        size_t row = (size_t)b * N_ + m0 + si * 16 + l16;
        *(s16x8*)(Xb + row * DIM + h * HD + quad * 16) = r0;
        *(s16x8*)(Xb + row * DIM + h * HD + quad * 16 + 8) = r1;
    }
}

// ---------------- Kernel 4: projection GEMM, 128x128 tile, double-buffered ----------
// Grid 384 (bm 0..63 x bn 0..5), 2x2 waves each owning 64x64 output (c[4][4]).
// Per kh: 16 MFMA on 8 ds_read_b128 (2:1, was 1.33:1) -> LDS/addr overhead per MFMA
// drops ~40%. A-panel shared by 6 bn-blocks 64 apart (same XCD). 64KB LDS ->
// 2 blocks/CU; grid 384 fully resident. Same (kk,kh) accumulation sequence per
// output element as the 128x64 version -> bit-identical results.
__global__ __launch_bounds__(256, 2)
void proj_kernel(const unsigned short* __restrict__ Xb,
                 const unsigned short* __restrict__ Wb,
                 const float* __restrict__ pb,
                 float* __restrict__ out) {
    int bid = blockIdx.x;
    int bm = bid % 64, bn = bid / 64;   // bn 0..5
    int tid = threadIdx.x, w = tid >> 6, ln = tid & 63;
    int l16 = ln & 15, quad = ln >> 4;
    int wm = w & 1, wn = w >> 1;        // wn 0..1

    __shared__ __attribute__((aligned(16))) unsigned short As[2][128 * 64];
    __shared__ __attribute__((aligned(16))) unsigned short Bs[2][128 * 64];

    int lr = ln >> 3;            // row-within-DMA-instr 0..7
    int gc = (ln & 7) ^ lr;      // swizzled global chunk this lane fetches

    const unsigned short* Ag = Xb + (size_t)(bm * 128 + w * 32 + lr) * DIM + gc * 8;
    const unsigned short* Bg = Wb + (size_t)(bn * 128 + w * 32 + lr) * DIM + gc * 8;

    f32x4 c[4][4];
    #pragma unroll
    for (int t = 0; t < 4; t++)
        #pragma unroll
        for (int u = 0; u < 4; u++) c[t][u] = (f32x4){0.f, 0.f, 0.f, 0.f};

    int sw = l16 & 7;            // row-swizzle term for fragment reads

#define PSTAGE(s, kk)                                                             \
    {                                                                             \
        _Pragma("unroll") for (int j = 0; j < 4; j++)                             \
            async_cp16(Ag + (size_t)j * 8 * DIM + (kk), &As[s][(w * 32 + j * 8) * 64]); \
        _Pragma("unroll") for (int j = 0; j < 4; j++)                             \
            async_cp16(Bg + (size_t)j * 8 * DIM + (kk), &Bs[s][(w * 32 + j * 8) * 64]); \
    }

    PSTAGE(0, 0);
    for (int it = 0; it < DIM / 64; it++) {
        int cur = it & 1;
        __syncthreads();                     // buf[cur] DMA complete; prior reads drained
        if (it + 1 < DIM / 64) PSTAGE(cur ^ 1, (it + 1) * 64);

        #pragma unroll
        for (int kh = 0; kh < 2; kh++) {
            s16x8 af[4], bf[4];
            #pragma unroll
            for (int t = 0; t < 4; t++) {
                int m = wm * 64 + t * 16 + l16;
                af[t] = *(const s16x8*)(&As[cur][m * 64 + (((kh * 4 + quad) ^ sw) * 8)]);
            }
            #pragma unroll
            for (int u = 0; u < 4; u++) {
                int n = wn * 64 + u * 16 + l16;
                bf[u] = *(const s16x8*)(&Bs[cur][n * 64 + (((kh * 4 + quad) ^ sw) * 8)]);
            }
            #pragma unroll
            for (int t = 0; t < 4; t++)
                #pragma unroll
                for (int u = 0; u < 4; u++)
                    c[t][u] = __builtin_amdgcn_mfma_f32_16x16x32_f16(asf(af[t]), asf(bf[u]), c[t][u], 0, 0, 0);
        }
    }
#undef PSTAGE

    int m0 = bm * 128 + wm * 64;
    int n0 = bn * 128 + wn * 64;
    #pragma unroll
    for (int u = 0; u < 4; u++) {
        float bias = pb[n0 + u * 16 + l16];
        #pragma unroll
        for (int t = 0; t < 4; t++)
            #pragma unroll
            for (int r = 0; r < 4; r++) {
                int row = m0 + t * 16 + quad * 4 + r;
                out[(size_t)row * DIM + n0 + u * 16 + l16] = c[t][u][r] + bias;
            }
    }
}

extern "C" void kernel_launch(void* const* d_in, const int* in_sizes, int n_in,
                              void* d_out, int out_size, void* d_ws, size_t ws_size,
                              hipStream_t stream) {
    const float* QKV = (const float*)d_in[0];
    const float* qw  = (const float*)d_in[1];
    const float* qb  = (const float*)d_in[2];
    const float* kw  = (const float*)d_in[3];
    const float* kb  = (const float*)d_in[4];
    const float* pw  = (const float*)d_in[5];
    const float* pb  = (const float*)d_in[6];
    float* out = (float*)d_out;

    size_t S = (size_t)BH * 65536;
    unsigned short* Qh = (unsigned short*)d_ws;
    unsigned short* Ql = Qh + S;
    unsigned short* Kh = Ql + S;
    unsigned short* Kl = Kh + S;
    unsigned short* Vh = Kl + S;
    unsigned short* Vl = Vh + S;
    unsigned short* Xb = Vl + S;                                // 8192*768
    unsigned short* Wb = Xb + (size_t)B_ * N_ * DIM;            // 768*768

    ln_pack_kernel<<<BH * 16 + CVT_BLOCKS, 256, 0, stream>>>(QKV, qw, qb, kw, kb,
                                                             Qh, Ql, Kh, Kl, Vh, Vl, pw, Wb);
    attn_kernel<<<BH * 8, 256, 0, stream>>>(Qh, Ql, Kh, Kl, Vh, Vl, Xb);
    proj_kernel<<<64 * 6, 256, 0, stream>>>(Xb, Wb, pb, out);
}